// Round 1
// baseline (42664.713 us; speedup 1.0000x reference)
//
#include <hip/hip_runtime.h>
#include <stdint.h>

#define LOG2E_F 1.4426950408889634f
#define SEQLEN 16384
#define NTAGS  1024
#define NB     32          // persistent blocks (1 per CU), each owns 32 rows
#define TPB    512
#define RB     32          // rows per block
#define GUARD_MAX 10000000

// ---- ws layout (bytes); requires ws_size >= 344064 ----
// 0      : wbuf   2*1024 u32 (double-buffered packed w words)
// 8192   : mdbuf  2*32  u32  (double-buffered packed per-block max-d words)
// 8448   : fs (f32), 8452: trans_sum (f32)
// 16384  : rm2[16384] f32  (per-step max_j feat*log2e)
// 81920  : emit partials 64*1024 f32
// packed word = (bf16(payload) << 16) | step_tag  -> self-validating, no fences needed

__global__ void crf_clear_k(uint32_t* __restrict__ wbuf, uint32_t* __restrict__ mdbuf) {
    const int tid = threadIdx.x;
    for (int i = tid; i < 2 * NTAGS; i += 256)
        __hip_atomic_store(&wbuf[i], 0xFFFFu, __ATOMIC_RELAXED, __HIP_MEMORY_SCOPE_AGENT);
    for (int i = tid; i < 2 * NB; i += 256)
        __hip_atomic_store(&mdbuf[i], 0xFFFFu, __ATOMIC_RELAXED, __HIP_MEMORY_SCOPE_AGENT);
}

__global__ void crf_rowmax_k(const float* __restrict__ feats, float* __restrict__ rm2) {
    const int t = blockIdx.x;
    const int tid = threadIdx.x; // 256
    const float* row = feats + (size_t)t * NTAGS;
    float m = row[tid];
    m = fmaxf(m, row[tid + 256]);
    m = fmaxf(m, row[tid + 512]);
    m = fmaxf(m, row[tid + 768]);
    for (int off = 32; off > 0; off >>= 1) m = fmaxf(m, __shfl_xor(m, off));
    __shared__ float sm[4];
    if ((tid & 63) == 0) sm[tid >> 6] = m;
    __syncthreads();
    if (tid == 0) rm2[t] = fmaxf(fmaxf(sm[0], sm[1]), fmaxf(sm[2], sm[3])) * LOG2E_F;
}

__global__ void crf_emit_k(const float* __restrict__ feats, const int* __restrict__ tags,
                           float* __restrict__ part) {
    __shared__ int tg[256];
    const int tid = threadIdx.x;
    const int b = blockIdx.x;      // 256 blocks: 64 t-chunks x 4 col-chunks
    const int c = b >> 2;
    const int jb = b & 3;
    tg[tid] = tags[c * 256 + tid];
    __syncthreads();
    const int j = jb * 256 + tid;
    float acc = 0.f;
#pragma unroll 8
    for (int k = 0; k < 256; ++k) acc += feats[(size_t)tg[k] * NTAGS + j];
    part[c * NTAGS + j] = acc;   // deterministic fixed-order partials
}

__global__ void crf_trans_k(const float* __restrict__ trans, const int* __restrict__ tags,
                            const int* __restrict__ start_p, float* __restrict__ tsum) {
    __shared__ float red[256];
    const int tid = threadIdx.x;
    const int start = *start_p;
    float acc = 0.f;
    for (int k = 0; k < 64; ++k) {
        const int t = tid * 64 + k;
        const int prev = (t == 0) ? start : tags[t - 1];
        acc += trans[(size_t)tags[t] * NTAGS + prev];
    }
    red[tid] = acc;
    __syncthreads();
    for (int s = 128; s > 0; s >>= 1) { if (tid < s) red[tid] += red[tid + s]; __syncthreads(); }
    if (tid == 0) *tsum = red[0];
}

__global__ __launch_bounds__(TPB, 1) void crf_forward_k(
    const float* __restrict__ feats, const float* __restrict__ trans,
    const int* __restrict__ start_p, const int* __restrict__ stop_p,
    uint32_t* __restrict__ wbuf, uint32_t* __restrict__ mdbuf,
    const float* __restrict__ rm2, float* __restrict__ fs_out)
{
    const int tid = threadIdx.x;
    const int b = blockIdx.x;
    const int r = tid >> 4;           // row within block 0..31
    const int c = tid & 15;           // 64-col chunk 0..15
    const int row = b * RB + r;       // global state j
    const bool c0 = (c == 0);

    __shared__ float w_lds[16 * 68];  // 68-stride padding: conflict-free b128 broadcast reads
    __shared__ float maxd_lds[NB];
    __shared__ float d_arr[RB];
    __shared__ int deadf;

    const int start = *start_p;

    // E = exp(T) row-chunk, resident in registers for the whole run
    float e2[64];
    {
        const float* tp = trans + (size_t)row * NTAGS + c * 64;
#pragma unroll
        for (int k = 0; k < 64; ++k) e2[k] = exp2f(tp[k] * LOG2E_F);
    }

    // w_0 = onehot(start), tag 0 (treats -10000 init as -inf; error ~ e^-9990, negligible)
    if (tid < RB) {
        const int j = b * RB + tid;
        const float w0 = (j == start) ? 1.0f : 0.0f;
        __hip_atomic_store(&wbuf[j], __float_as_uint(w0) & 0xFFFF0000u,
                           __ATOMIC_RELAXED, __HIP_MEMORY_SCOPE_AGENT);
    }
    if (tid == 0) deadf = 0;
    __syncthreads();

    double S = 0.0;
    float feat_cur = 0.f, rm2_cur = 0.f;
    if (c0) { feat_cur = feats[row]; rm2_cur = rm2[0]; }

    const int i0 = tid * 2, i1 = tid * 2 + 1;
    const int s0 = (i0 >> 6) * 68 + (i0 & 63);

    for (int t = 0; t < SEQLEN; ++t) {
        uint32_t* wb = wbuf + (t & 1) * NTAGS;
        const uint32_t tag = (uint32_t)t;

        // prefetch next step's feat/rowmax (off critical path)
        float feat_nxt = 0.f, rm2_nxt = 0.f;
        if (c0 && t + 1 < SEQLEN) {
            feat_nxt = feats[(size_t)(t + 1) * NTAGS + row];
            rm2_nxt = rm2[t + 1];
        }

        // poll my two packed w words (the poll IS the data read)
        uint32_t wa, wbv;
        int guard = 0;
        for (;;) {
            wa  = __hip_atomic_load(&wb[i0], __ATOMIC_RELAXED, __HIP_MEMORY_SCOPE_AGENT);
            wbv = __hip_atomic_load(&wb[i1], __ATOMIC_RELAXED, __HIP_MEMORY_SCOPE_AGENT);
            if ((((wa ^ tag) | (wbv ^ tag)) & 0xFFFFu) == 0u) break;
            if (++guard > GUARD_MAX) { deadf = 1; break; }
        }
        *(float2*)&w_lds[s0] = make_float2(__uint_as_float(wa & 0xFFFF0000u),
                                           __uint_as_float(wbv & 0xFFFF0000u));
        if (tid < NB && t > 0) {
            uint32_t* mb = mdbuf + (t & 1) * NB;
            uint32_t md;
            guard = 0;
            for (;;) {
                md = __hip_atomic_load(&mb[tid], __ATOMIC_RELAXED, __HIP_MEMORY_SCOPE_AGENT);
                if ((md & 0xFFFFu) == tag) break;
                if (++guard > GUARD_MAX) { deadf = 1; break; }
            }
            maxd_lds[tid] = __uint_as_float(md & 0xFFFF0000u);
        }
        __syncthreads();
        if (deadf) break;   // uniform abort path (no hangs)

        // d_row partial: 64 reg-resident E entries x LDS-broadcast w
        float acc = 0.f;
        {
            const float* wl = &w_lds[c * 68];
#pragma unroll
            for (int k4 = 0; k4 < 16; ++k4) {
                const float4 wv = *(const float4*)&wl[k4 * 4];
                acc = fmaf(e2[k4 * 4 + 0], wv.x, acc);
                acc = fmaf(e2[k4 * 4 + 1], wv.y, acc);
                acc = fmaf(e2[k4 * 4 + 2], wv.z, acc);
                acc = fmaf(e2[k4 * 4 + 3], wv.w, acc);
            }
        }
        acc += __shfl_xor(acc, 8);
        acc += __shfl_xor(acc, 4);
        acc += __shfl_xor(acc, 2);
        acc += __shfl_xor(acc, 1);   // 16 lanes of a row -> full dot product

        if (c0) {
            float C;
            if (t == 0) {
                C = rm2_cur + 7.0f;
            } else {
                float md = maxd_lds[0];
                for (int q = 1; q < NB; ++q) md = fmaxf(md, maxd_lds[q]);
                C = rm2_cur + __log2f(md);   // identical in every block (same inputs)
            }
            S += (double)C;
            const float wn = acc * exp2f(fmaf(feat_cur, LOG2E_F, -C));
            uint32_t bits = __float_as_uint(wn);
            bits += 0x7FFFu + ((bits >> 16) & 1u);   // round-to-nearest bf16 (no bias)
            __hip_atomic_store(&wbuf[((t + 1) & 1) * NTAGS + row],
                               (bits & 0xFFFF0000u) | (tag + 1u),
                               __ATOMIC_RELAXED, __HIP_MEMORY_SCOPE_AGENT);
            d_arr[r] = acc;
        }
        __syncthreads();
        if (tid == 0) {
            float md = d_arr[0];
            for (int q = 1; q < RB; ++q) md = fmaxf(md, d_arr[q]);
            uint32_t bits = __float_as_uint(md);
            bits += 0x7FFFu + ((bits >> 16) & 1u);
            __hip_atomic_store(&mdbuf[((t + 1) & 1) * NB + b],
                               (bits & 0xFFFF0000u) | (tag + 1u),
                               __ATOMIC_RELAXED, __HIP_MEMORY_SCOPE_AGENT);
        }
        feat_cur = feat_nxt; rm2_cur = rm2_nxt;
    }

    // forward_score = ln2 * (S + log2( sum_j w_final[j] * exp(T[stop,j]) ))
    if (b == 0) {
        const uint32_t ftag = (uint32_t)SEQLEN;   // final words live in buffer (16384&1)==0
        uint32_t wa, wbv;
        int guard = 0;
        for (;;) {
            wa  = __hip_atomic_load(&wbuf[i0], __ATOMIC_RELAXED, __HIP_MEMORY_SCOPE_AGENT);
            wbv = __hip_atomic_load(&wbuf[i1], __ATOMIC_RELAXED, __HIP_MEMORY_SCOPE_AGENT);
            if ((((wa ^ ftag) | (wbv ^ ftag)) & 0xFFFFu) == 0u) break;
            if (++guard > GUARD_MAX) break;
        }
        const int stop = *stop_p;
        const float v0 = __uint_as_float(wa & 0xFFFF0000u);
        const float v1 = __uint_as_float(wbv & 0xFFFF0000u);
        float p = v0 * exp2f(trans[(size_t)stop * NTAGS + i0] * LOG2E_F)
                + v1 * exp2f(trans[(size_t)stop * NTAGS + i1] * LOG2E_F);
        __shared__ float red[TPB];
        red[tid] = p;
        __syncthreads();
        for (int s = TPB / 2; s > 0; s >>= 1) {
            if (tid < s) red[tid] += red[tid + s];
            __syncthreads();
        }
        if (tid == 0)
            fs_out[0] = (float)(0.6931471805599453 * (S + (double)__log2f(red[0])));
    }
}

__global__ void crf_out_k(const float* __restrict__ fsp, const float* __restrict__ tsum,
                          const float* __restrict__ part, const float* __restrict__ trans,
                          const int* __restrict__ tags, const int* __restrict__ stop_p,
                          float* __restrict__ out) {
    const int j = threadIdx.x; // 1024
    float e = 0.f;
    for (int cc = 0; cc < 64; ++cc) e += part[cc * NTAGS + j];
    const int stop = *stop_p;
    const int last = tags[SEQLEN - 1];
    out[j] = fsp[0] - (tsum[0] + e + trans[(size_t)stop * NTAGS + last]);
}

extern "C" void kernel_launch(void* const* d_in, const int* in_sizes, int n_in,
                              void* d_out, int out_size, void* d_ws, size_t ws_size,
                              hipStream_t stream) {
    const float* feats = (const float*)d_in[0];
    const float* trans = (const float*)d_in[1];
    const int* tags    = (const int*)d_in[2];
    const int* start_p = (const int*)d_in[3];
    const int* stop_p  = (const int*)d_in[4];
    float* out = (float*)d_out;

    char* ws = (char*)d_ws;
    uint32_t* wbuf  = (uint32_t*)(ws + 0);
    uint32_t* mdbuf = (uint32_t*)(ws + 8192);
    float* fs   = (float*)(ws + 8448);
    float* tsum = (float*)(ws + 8452);
    float* rm2  = (float*)(ws + 16384);
    float* part = (float*)(ws + 81920);

    crf_clear_k<<<1, 256, 0, stream>>>(wbuf, mdbuf);
    crf_rowmax_k<<<SEQLEN, 256, 0, stream>>>(feats, rm2);
    crf_emit_k<<<256, 256, 0, stream>>>(feats, tags, part);
    crf_trans_k<<<1, 256, 0, stream>>>(trans, tags, start_p, tsum);
    crf_forward_k<<<NB, TPB, 0, stream>>>(feats, trans, start_p, stop_p, wbuf, mdbuf, rm2, fs);
    crf_out_k<<<1, 1024, 0, stream>>>(fs, tsum, part, trans, tags, stop_p, out);
}

// Round 3
// 29516.132 us; speedup vs baseline: 1.4455x; 1.4455x over previous
//
#include <hip/hip_runtime.h>
#include <stdint.h>

#define LOG2E_F 1.4426950408889634f
#define LN2_D   0.6931471805599453
#define SEQLEN 16384
#define NTAGS  1024
#define NSEG   8
#define SEGLEN (SEQLEN / NSEG)   // 2048
#define NREC   (2 * NSEG)        // 16 recurrences (8 fwd + 8 bwd)
#define BPR    16                // blocks per recurrence
#define TPB    512
#define ROWS   64                // rows per block
#define GUARD_MAX 3000000

// ---- ws layout (bytes), total < 262400 (R1 used 344064 OK) ----
// 0      : wbufs [16][2][1024] u32   (double-buffered packed words: (bf16<<16)|tag)
// 131072 : rm2  [16384] f32          (per-step max_j feat*log2e)
// 196608 : part [16][1024] f32       (emit partials)
// 262144 : Ssum [16] double          (per-recurrence scale sums)
// 262272 : fs f32 ; 262276 : tsum f32

__global__ void crf_clear_k(uint32_t* __restrict__ wbufs) {
    const int tid = threadIdx.x;
    for (int i = tid; i < NREC * 2 * NTAGS; i += 256)
        __hip_atomic_store(&wbufs[i], 0xFFFFu, __ATOMIC_RELAXED, __HIP_MEMORY_SCOPE_AGENT);
}

__global__ void crf_rowmax_k(const float* __restrict__ feats, float* __restrict__ rm2) {
    const int t = blockIdx.x;
    const int tid = threadIdx.x; // 256
    const float* row = feats + (size_t)t * NTAGS;
    float m = row[tid];
    m = fmaxf(m, row[tid + 256]);
    m = fmaxf(m, row[tid + 512]);
    m = fmaxf(m, row[tid + 768]);
    for (int off = 32; off > 0; off >>= 1) m = fmaxf(m, __shfl_xor(m, off));
    __shared__ float sm[4];
    if ((tid & 63) == 0) sm[tid >> 6] = m;
    __syncthreads();
    if (tid == 0) rm2[t] = fmaxf(fmaxf(sm[0], sm[1]), fmaxf(sm[2], sm[3])) * LOG2E_F;
}

__global__ void crf_emit_k(const float* __restrict__ feats, const int* __restrict__ tags,
                           float* __restrict__ part) {
    __shared__ int tg[1024];
    const int tid = threadIdx.x;          // 256
    const int b = blockIdx.x;             // 64 blocks: 16 t-chunks x 4 col-chunks
    const int cch = b >> 2;
    const int jb = b & 3;
    for (int q = tid; q < 1024; q += 256) tg[q] = tags[cch * 1024 + q];
    __syncthreads();
    const int j = jb * 256 + tid;
    float acc = 0.f;
#pragma unroll 8
    for (int k = 0; k < 1024; ++k) acc += feats[(size_t)tg[k] * NTAGS + j];
    part[cch * NTAGS + j] = acc;          // deterministic fixed-order partials
}

__global__ void crf_trans_k(const float* __restrict__ trans, const int* __restrict__ tags,
                            const int* __restrict__ start_p, float* __restrict__ tsum) {
    __shared__ float red[256];
    const int tid = threadIdx.x;
    const int start = *start_p;
    float acc = 0.f;
    for (int k = 0; k < 64; ++k) {
        const int t = tid * 64 + k;
        const int prev = (t == 0) ? start : tags[t - 1];
        acc += trans[(size_t)tags[t] * NTAGS + prev];
    }
    red[tid] = acc;
    __syncthreads();
    for (int s = 128; s > 0; s >>= 1) { if (tid < s) red[tid] += red[tid + s]; __syncthreads(); }
    if (tid == 0) *tsum = red[0];
}

// One kernel runs all 16 recurrences. rec = blockIdx&15 (so a recurrence's 16
// blocks land 16-apart in dispatch order -> likely same XCD, helps LLC locality;
// correctness does not depend on it: all comms are agent-scope atomics).
__global__ __launch_bounds__(TPB, 2) void crf_scan_k(
    const float* __restrict__ feats, const float* __restrict__ trans,
    uint32_t* __restrict__ wbufs, const float* __restrict__ rm2,
    double* __restrict__ Ssum)
{
    const int tid = threadIdx.x;
    const int rec = blockIdx.x & (NREC - 1);
    const int rank = blockIdx.x >> 4;       // 0..15
    const int seg = rec & (NSEG - 1);
    const int bwd = rec >> 3;               // 0 = forward, 1 = backward (transpose)
    const int a = seg * SEGLEN;
    const int r = tid >> 3;                 // row-in-block 0..63
    const int c = tid & 7;                  // 128-col chunk 0..7
    const int row = rank * ROWS + r;        // global state index
    const bool c0 = (c == 0);
    uint32_t* wbuf = wbufs + rec * (2 * NTAGS);

    __shared__ float w_lds[8 * 132];        // 8 chunks x 128, stride 132: conflict-free
    __shared__ float wmax_lds[8];
    __shared__ int deadf;

    // E chunk resident in registers. fwd: E[row, c*128+k] = exp(T[row, col]).
    // bwd: (E^T)[row, c*128+k] = exp(T[col, row]) (one-time gathered loads).
    float e2[128];
    if (!bwd) {
        const float* tp = trans + (size_t)row * NTAGS + c * 128;
#pragma unroll
        for (int k = 0; k < 128; ++k) e2[k] = exp2f(tp[k] * LOG2E_F);
    } else {
        const float* tp = trans + (size_t)(c * 128) * NTAGS + row;
#pragma unroll 8
        for (int k = 0; k < 128; ++k) e2[k] = exp2f(tp[(size_t)k * NTAGS] * LOG2E_F);
    }

    if (tid == 0) deadf = 0;

    // Initial publish (tag 0). fwd: uniform ones. bwd: D_{b-1}*1 scaled by 2^-C0.
    double S = 0.0;
    if (!bwd) {
        if (c0)
            __hip_atomic_store(&wbuf[row], __float_as_uint(1.0f) & 0xFFFF0000u,
                               __ATOMIC_RELAXED, __HIP_MEMORY_SCOPE_AGENT);
    } else {
        const float C0 = rm2[a + SEGLEN - 1] + 10.0f;
        S = (double)C0;
        if (c0) {
            const float fL = feats[(size_t)(a + SEGLEN - 1) * NTAGS + row] * LOG2E_F;
            uint32_t bits = __float_as_uint(exp2f(fL - C0));
            bits += 0x7FFFu + ((bits >> 16) & 1u);   // round-to-nearest bf16
            __hip_atomic_store(&wbuf[row], bits & 0xFFFF0000u,
                               __ATOMIC_RELAXED, __HIP_MEMORY_SCOPE_AGENT);
        }
    }
    __syncthreads();

    // feat index applied at publish of tag k+1:
    //   fwd: a+k          (k = 0..SEGLEN-1)
    //   bwd: b-2-k if k <= SEGLEN-2, else none (final publish = M^T*1, no D)
    float featL_cur = 0.f, rm2_cur = 0.f;
    {
        const int f0 = bwd ? (a + SEGLEN - 2) : a;
        rm2_cur = rm2[f0];
        if (c0) featL_cur = feats[(size_t)f0 * NTAGS + row] * LOG2E_F;
    }

    const int i0 = tid * 2;
    const int sidx = (i0 >> 7) * 132 + (i0 & 127);

    for (int k = 0; k < SEGLEN; ++k) {
        const uint32_t tag = (uint32_t)k;
        uint32_t* wb = wbuf + (k & 1) * NTAGS;

        uint32_t wa, wv;
        {
            int guard = 0;
            for (;;) {
                wa = __hip_atomic_load(&wb[i0],     __ATOMIC_RELAXED, __HIP_MEMORY_SCOPE_AGENT);
                wv = __hip_atomic_load(&wb[i0 + 1], __ATOMIC_RELAXED, __HIP_MEMORY_SCOPE_AGENT);
                if ((((wa ^ tag) | (wv ^ tag)) & 0xFFFFu) == 0u) break;
                if (++guard > GUARD_MAX) { deadf = 1; break; }
            }
        }
        // prefetch next step's feat/rm2 (hidden under this step's compute)
        float featL_nxt = 0.f, rm2_nxt = 0.f;
        {
            const int kn = k + 1;
            int fn = -1;
            if (kn < SEGLEN) fn = bwd ? ((kn <= SEGLEN - 2) ? (a + SEGLEN - 2 - kn) : -1)
                                      : (a + kn);
            if (fn >= 0) {
                rm2_nxt = rm2[fn];
                if (c0) featL_nxt = feats[(size_t)fn * NTAGS + row] * LOG2E_F;
            }
        }
        __syncthreads();               // prev-iter LDS reads complete; deadf visible
        if (deadf) break;              // uniform abort (no hang)

        const float w0f = __uint_as_float(wa & 0xFFFF0000u);
        const float w1f = __uint_as_float(wv & 0xFFFF0000u);
        w_lds[sidx] = w0f; w_lds[sidx + 1] = w1f;
        float m2 = fmaxf(w0f, w1f);
#pragma unroll
        for (int o = 32; o > 0; o >>= 1) m2 = fmaxf(m2, __shfl_xor(m2, o));
        if ((tid & 63) == 0) wmax_lds[tid >> 6] = m2;
        __syncthreads();

        float mw = wmax_lds[0];
#pragma unroll
        for (int q = 1; q < 8; ++q) mw = fmaxf(mw, wmax_lds[q]);
        const float C = rm2_cur + __log2f(mw) + 10.0f;  // identical in every block
        S += (double)C;

        float acc = 0.f;
        const float* wl = &w_lds[c * 132];
#pragma unroll
        for (int k4 = 0; k4 < 32; ++k4) {
            const float4 w4 = *(const float4*)&wl[k4 * 4];
            acc = fmaf(e2[k4 * 4 + 0], w4.x, acc);
            acc = fmaf(e2[k4 * 4 + 1], w4.y, acc);
            acc = fmaf(e2[k4 * 4 + 2], w4.z, acc);
            acc = fmaf(e2[k4 * 4 + 3], w4.w, acc);
        }
        acc += __shfl_xor(acc, 4);
        acc += __shfl_xor(acc, 2);
        acc += __shfl_xor(acc, 1);     // 8 lanes of a row -> full dot product

        if (c0) {
            const float wn = acc * exp2f(featL_cur - C);
            uint32_t bits = __float_as_uint(wn);
            bits += 0x7FFFu + ((bits >> 16) & 1u);
            __hip_atomic_store(&wbuf[((k + 1) & 1) * NTAGS + row],
                               (bits & 0xFFFF0000u) | ((tag + 1u) & 0xFFFFu),
                               __ATOMIC_RELAXED, __HIP_MEMORY_SCOPE_AGENT);
        }
        featL_cur = featL_nxt; rm2_cur = rm2_nxt;
    }

    if (rank == 0 && tid == 0) Ssum[rec] = S;
}

// Serial stitch: v0 = init; for s: c = LSE(z_s+v)-LSE(z_s); v = y_s + c.
// Runs after crf_scan_k on the same stream (tag SEGLEN words live in buffer 0).
__global__ void crf_stitch_k(const uint32_t* __restrict__ wbufs,
                             const double* __restrict__ Ssum,
                             const float* __restrict__ trans,
                             const int* __restrict__ start_p, const int* __restrict__ stop_p,
                             float* __restrict__ fs_out)
{
    const int j = threadIdx.x;   // 1024
    __shared__ float sred[16];

    auto bmax = [&](float x) -> float {
#pragma unroll
        for (int o = 32; o > 0; o >>= 1) x = fmaxf(x, __shfl_xor(x, o));
        if ((j & 63) == 0) sred[j >> 6] = x;
        __syncthreads();
        float m = sred[0];
#pragma unroll
        for (int q = 1; q < 16; ++q) m = fmaxf(m, sred[q]);
        __syncthreads();
        return m;
    };
    auto bsum = [&](float x) -> float {
#pragma unroll
        for (int o = 32; o > 0; o >>= 1) x += __shfl_xor(x, o);
        if ((j & 63) == 0) sred[j >> 6] = x;
        __syncthreads();
        float s = 0.f;
#pragma unroll
        for (int q = 0; q < 16; ++q) s += sred[q];
        __syncthreads();
        return s;
    };

    float v = (j == *start_p) ? 0.0f : -10000.0f;
    for (int s = 0; s < NSEG; ++s) {
        const float yp = __uint_as_float(wbufs[s * 2048 + j] & 0xFFFF0000u);
        const float zp = __uint_as_float(wbufs[(NSEG + s) * 2048 + j] & 0xFFFF0000u);
        const float y = (float)(LN2_D * ((double)__log2f(yp) + Ssum[s]));
        const float z = (float)(LN2_D * ((double)__log2f(zp) + Ssum[NSEG + s]));
        const float m1 = bmax(z + v);
        const float s1 = bsum(__expf(z + v - m1));
        const float m2 = bmax(z);
        const float s2 = bsum(__expf(z - m2));
        v = y + ((m1 + __logf(s1)) - (m2 + __logf(s2)));
    }
    const float tr = trans[(size_t)(*stop_p) * NTAGS + j];
    const float m = bmax(v + tr);
    const float ss = bsum(__expf(v + tr - m));
    if (j == 0) fs_out[0] = m + __logf(ss);
}

__global__ void crf_out_k(const float* __restrict__ fsp, const float* __restrict__ tsum,
                          const float* __restrict__ part, const float* __restrict__ trans,
                          const int* __restrict__ tags, const int* __restrict__ stop_p,
                          float* __restrict__ out) {
    const int j = threadIdx.x; // 1024
    float e = 0.f;
    for (int cc = 0; cc < 16; ++cc) e += part[cc * NTAGS + j];
    const int stop = *stop_p;
    const int last = tags[SEQLEN - 1];
    out[j] = fsp[0] - (tsum[0] + e + trans[(size_t)stop * NTAGS + last]);
}

extern "C" void kernel_launch(void* const* d_in, const int* in_sizes, int n_in,
                              void* d_out, int out_size, void* d_ws, size_t ws_size,
                              hipStream_t stream) {
    const float* feats = (const float*)d_in[0];
    const float* trans = (const float*)d_in[1];
    const int* tags    = (const int*)d_in[2];
    const int* start_p = (const int*)d_in[3];
    const int* stop_p  = (const int*)d_in[4];
    float* out = (float*)d_out;

    char* ws = (char*)d_ws;
    uint32_t* wbufs = (uint32_t*)(ws + 0);
    float* rm2      = (float*)(ws + 131072);
    float* part     = (float*)(ws + 196608);
    double* Ssum    = (double*)(ws + 262144);
    float* fs       = (float*)(ws + 262272);
    float* tsum     = (float*)(ws + 262276);

    crf_clear_k<<<1, 256, 0, stream>>>(wbufs);
    crf_rowmax_k<<<SEQLEN, 256, 0, stream>>>(feats, rm2);
    crf_emit_k<<<64, 256, 0, stream>>>(feats, tags, part);
    crf_trans_k<<<1, 256, 0, stream>>>(trans, tags, start_p, tsum);
    crf_scan_k<<<NREC * BPR, TPB, 0, stream>>>(feats, trans, wbufs, rm2, Ssum);
    crf_stitch_k<<<1, 1024, 0, stream>>>(wbufs, Ssum, trans, start_p, stop_p, fs);
    crf_out_k<<<1, 1024, 0, stream>>>(fs, tsum, part, trans, tags, stop_p, out);
}

// Round 4
// 8912.800 us; speedup vs baseline: 4.7869x; 3.3117x over previous
//
#include <hip/hip_runtime.h>
#include <stdint.h>

#define LOG2E_F 1.4426950408889634f
#define LN2_D   0.6931471805599453
#define SEQLEN 16384
#define NTAGS  1024
#define NSEG   8
#define SEGLEN (SEQLEN / NSEG)   // 2048
#define NREC   (2 * NSEG)        // 16 recurrences (8 fwd + 8 bwd)
#define BPR    16                // blocks per recurrence
#define TPB    512
#define ROWS   64                // rows per block
#define GUARD_MAX 3000000

// ---- ws layout (bytes) ----
// 0      : wbufs [16][2][1024] u32   (double-buffered packed words: (bf16<<16)|tag)
// 131072 : rm2  [16384] f32
// 196608 : part [16][1024] f32
// 262144 : Ssum [16] double
// 262272 : fs f32 ; 262276 : tsum f32

// Literal-constant-index repetition (guarantees SROA: e2[] stays in VGPRs)
#define REP4(M, B)   M(B) M((B) + 1) M((B) + 2) M((B) + 3)
#define REP16(M, B)  REP4(M, B) REP4(M, (B) + 4) REP4(M, (B) + 8) REP4(M, (B) + 12)
#define REP32(M, B)  REP16(M, B) REP16(M, (B) + 16)
#define REP64(M, B)  REP32(M, B) REP32(M, (B) + 32)
#define REP128(M, B) REP64(M, B) REP64(M, (B) + 64)

__global__ void crf_clear_k(uint32_t* __restrict__ wbufs) {
    const int tid = threadIdx.x;
    for (int i = tid; i < NREC * 2 * NTAGS; i += 256)
        __hip_atomic_store(&wbufs[i], 0xFFFFu, __ATOMIC_RELAXED, __HIP_MEMORY_SCOPE_AGENT);
}

__global__ void crf_rowmax_k(const float* __restrict__ feats, float* __restrict__ rm2) {
    const int t = blockIdx.x;
    const int tid = threadIdx.x; // 256
    const float* row = feats + (size_t)t * NTAGS;
    float m = row[tid];
    m = fmaxf(m, row[tid + 256]);
    m = fmaxf(m, row[tid + 512]);
    m = fmaxf(m, row[tid + 768]);
    for (int off = 32; off > 0; off >>= 1) m = fmaxf(m, __shfl_xor(m, off));
    __shared__ float sm[4];
    if ((tid & 63) == 0) sm[tid >> 6] = m;
    __syncthreads();
    if (tid == 0) rm2[t] = fmaxf(fmaxf(sm[0], sm[1]), fmaxf(sm[2], sm[3])) * LOG2E_F;
}

__global__ void crf_emit_k(const float* __restrict__ feats, const int* __restrict__ tags,
                           float* __restrict__ part) {
    __shared__ int tg[1024];
    const int tid = threadIdx.x;          // 256
    const int b = blockIdx.x;             // 64 blocks: 16 t-chunks x 4 col-chunks
    const int cch = b >> 2;
    const int jb = b & 3;
    for (int q = tid; q < 1024; q += 256) tg[q] = tags[cch * 1024 + q];
    __syncthreads();
    const int j = jb * 256 + tid;
    float acc = 0.f;
#pragma unroll 8
    for (int k = 0; k < 1024; ++k) acc += feats[(size_t)tg[k] * NTAGS + j];
    part[cch * NTAGS + j] = acc;          // deterministic fixed-order partials
}

__global__ void crf_trans_k(const float* __restrict__ trans, const int* __restrict__ tags,
                            const int* __restrict__ start_p, float* __restrict__ tsum) {
    __shared__ float red[256];
    const int tid = threadIdx.x;
    const int start = *start_p;
    float acc = 0.f;
    for (int k = 0; k < 64; ++k) {
        const int t = tid * 64 + k;
        const int prev = (t == 0) ? start : tags[t - 1];
        acc += trans[(size_t)tags[t] * NTAGS + prev];
    }
    red[tid] = acc;
    __syncthreads();
    for (int s = 128; s > 0; s >>= 1) { if (tid < s) red[tid] += red[tid + s]; __syncthreads(); }
    if (tid == 0) *tsum = red[0];
}

__global__ __launch_bounds__(TPB, 2) void crf_scan_k(
    const float* __restrict__ feats, const float* __restrict__ trans,
    uint32_t* __restrict__ wbufs, const float* __restrict__ rm2,
    double* __restrict__ Ssum)
{
    const int tid = threadIdx.x;
    const int rec = blockIdx.x & (NREC - 1);
    const int rank = blockIdx.x >> 4;       // 0..15
    const int seg = rec & (NSEG - 1);
    const int bwd = rec >> 3;               // 0 = forward, 1 = backward (transpose)
    const int a = seg * SEGLEN;
    const int r = tid >> 3;                 // row-in-block 0..63
    const int c = tid & 7;                  // 128-col chunk 0..7
    const int row = rank * ROWS + r;        // global state index
    const bool c0 = (c == 0);
    uint32_t* wbuf = wbufs + rec * (2 * NTAGS);

    __shared__ float w_lds[8 * 132];        // stride 132: conflict-free float4 broadcast
    __shared__ float wmax_lds[8];
    __shared__ int deadf;

    // E chunk, VGPR-resident. fwd: E[row, c*128+k] = exp(T[row, c*128+k]), stride 1.
    // bwd: (E^T)[row, c*128+k] = exp(T[c*128+k, row]), stride NTAGS. Single code
    // path, literal indices everywhere -> SROA keeps e2 in registers.
    float e2[128];
    {
        const size_t estride = bwd ? (size_t)NTAGS : 1;
        const float* tp = bwd ? (trans + (size_t)(c * 128) * NTAGS + row)
                              : (trans + (size_t)row * NTAGS + c * 128);
#define EI(K) e2[K] = exp2f(tp[(size_t)(K) * estride] * LOG2E_F);
        REP128(EI, 0)
#undef EI
    }

    if (tid == 0) deadf = 0;

    // Initial publish (tag 0). fwd: uniform ones. bwd: D_{last}*1 scaled by 2^-C0.
    double S = 0.0;
    if (!bwd) {
        if (c0)
            __hip_atomic_store(&wbuf[row], __float_as_uint(1.0f) & 0xFFFF0000u,
                               __ATOMIC_RELAXED, __HIP_MEMORY_SCOPE_AGENT);
    } else {
        const float C0 = rm2[a + SEGLEN - 1] + 10.0f;
        S = (double)C0;
        if (c0) {
            const float fL = feats[(size_t)(a + SEGLEN - 1) * NTAGS + row] * LOG2E_F;
            uint32_t bits = __float_as_uint(exp2f(fL - C0));
            bits += 0x7FFFu + ((bits >> 16) & 1u);   // round-to-nearest bf16
            __hip_atomic_store(&wbuf[row], bits & 0xFFFF0000u,
                               __ATOMIC_RELAXED, __HIP_MEMORY_SCOPE_AGENT);
        }
    }
    __syncthreads();

    // feat index applied at publish of tag k+1:
    //   fwd: a+k ; bwd: (a+SEGLEN-2)-k while k <= SEGLEN-2 (final publish has no D)
    float featL_cur = 0.f, rm2_cur = 0.f;
    {
        const int f0 = bwd ? (a + SEGLEN - 2) : a;
        rm2_cur = rm2[f0];
        if (c0) featL_cur = feats[(size_t)f0 * NTAGS + row] * LOG2E_F;
    }

    const int i0 = tid * 2;
    const int sidx = (i0 >> 7) * 132 + (i0 & 127);

    for (int k = 0; k < SEGLEN; ++k) {
        const uint32_t tag = (uint32_t)k;
        uint32_t* wb = wbuf + (k & 1) * NTAGS;

        uint32_t wa, wv;
        {
            int guard = 0;
            for (;;) {
                wa = __hip_atomic_load(&wb[i0],     __ATOMIC_RELAXED, __HIP_MEMORY_SCOPE_AGENT);
                wv = __hip_atomic_load(&wb[i0 + 1], __ATOMIC_RELAXED, __HIP_MEMORY_SCOPE_AGENT);
                if ((((wa ^ tag) | (wv ^ tag)) & 0xFFFFu) == 0u) break;
                if (++guard > GUARD_MAX) { deadf = 1; break; }
            }
        }
        // prefetch next step's feat/rm2 (hidden under this step's compute)
        float featL_nxt = 0.f, rm2_nxt = 0.f;
        {
            const int kn = k + 1;
            int fn = -1;
            if (kn < SEGLEN) fn = bwd ? ((kn <= SEGLEN - 2) ? (a + SEGLEN - 2 - kn) : -1)
                                      : (a + kn);
            if (fn >= 0) {
                rm2_nxt = rm2[fn];
                if (c0) featL_nxt = feats[(size_t)fn * NTAGS + row] * LOG2E_F;
            }
        }
        __syncthreads();               // prev-iter LDS reads complete; deadf visible
        if (deadf) break;              // uniform abort (no hang)

        const float w0f = __uint_as_float(wa & 0xFFFF0000u);
        const float w1f = __uint_as_float(wv & 0xFFFF0000u);
        w_lds[sidx] = w0f; w_lds[sidx + 1] = w1f;
        float m2 = fmaxf(w0f, w1f);
#pragma unroll
        for (int o = 32; o > 0; o >>= 1) m2 = fmaxf(m2, __shfl_xor(m2, o));
        if ((tid & 63) == 0) wmax_lds[tid >> 6] = m2;
        __syncthreads();

        float mw = wmax_lds[0];
#pragma unroll
        for (int q = 1; q < 8; ++q) mw = fmaxf(mw, wmax_lds[q]);
        const float C = rm2_cur + __log2f(mw) + 10.0f;  // identical in every block
        S += (double)C;

        float acc = 0.f;
        const float* wl = &w_lds[c * 132];
#define FM(K4) { const float4 w4 = *(const float4*)&wl[(K4) * 4];      \
                 acc = fmaf(e2[(K4) * 4 + 0], w4.x, acc);               \
                 acc = fmaf(e2[(K4) * 4 + 1], w4.y, acc);               \
                 acc = fmaf(e2[(K4) * 4 + 2], w4.z, acc);               \
                 acc = fmaf(e2[(K4) * 4 + 3], w4.w, acc); }
        REP32(FM, 0)
#undef FM
        acc += __shfl_xor(acc, 4);
        acc += __shfl_xor(acc, 2);
        acc += __shfl_xor(acc, 1);     // 8 lanes of a row -> full dot product

        if (c0) {
            const float wn = acc * exp2f(featL_cur - C);
            uint32_t bits = __float_as_uint(wn);
            bits += 0x7FFFu + ((bits >> 16) & 1u);
            __hip_atomic_store(&wbuf[((k + 1) & 1) * NTAGS + row],
                               (bits & 0xFFFF0000u) | ((tag + 1u) & 0xFFFFu),
                               __ATOMIC_RELAXED, __HIP_MEMORY_SCOPE_AGENT);
        }
        featL_cur = featL_nxt; rm2_cur = rm2_nxt;
    }

    if (rank == 0 && tid == 0) Ssum[rec] = S;
}

// Serial stitch: v0 = init; for s: c = LSE(z_s+v)-LSE(z_s); v = y_s + c.
__global__ void crf_stitch_k(const uint32_t* __restrict__ wbufs,
                             const double* __restrict__ Ssum,
                             const float* __restrict__ trans,
                             const int* __restrict__ start_p, const int* __restrict__ stop_p,
                             float* __restrict__ fs_out)
{
    const int j = threadIdx.x;   // 1024
    __shared__ float sred[16];

    auto bmax = [&](float x) -> float {
#pragma unroll
        for (int o = 32; o > 0; o >>= 1) x = fmaxf(x, __shfl_xor(x, o));
        if ((j & 63) == 0) sred[j >> 6] = x;
        __syncthreads();
        float m = sred[0];
#pragma unroll
        for (int q = 1; q < 16; ++q) m = fmaxf(m, sred[q]);
        __syncthreads();
        return m;
    };
    auto bsum = [&](float x) -> float {
#pragma unroll
        for (int o = 32; o > 0; o >>= 1) x += __shfl_xor(x, o);
        if ((j & 63) == 0) sred[j >> 6] = x;
        __syncthreads();
        float s = 0.f;
#pragma unroll
        for (int q = 0; q < 16; ++q) s += sred[q];
        __syncthreads();
        return s;
    };

    float v = (j == *start_p) ? 0.0f : -10000.0f;
    for (int s = 0; s < NSEG; ++s) {
        const float yp = __uint_as_float(wbufs[s * 2048 + j] & 0xFFFF0000u);
        const float zp = __uint_as_float(wbufs[(NSEG + s) * 2048 + j] & 0xFFFF0000u);
        const float y = (float)(LN2_D * ((double)__log2f(yp) + Ssum[s]));
        const float z = (float)(LN2_D * ((double)__log2f(zp) + Ssum[NSEG + s]));
        const float m1 = bmax(z + v);
        const float s1 = bsum(__expf(z + v - m1));
        const float m2 = bmax(z);
        const float s2 = bsum(__expf(z - m2));
        v = y + ((m1 + __logf(s1)) - (m2 + __logf(s2)));
    }
    const float tr = trans[(size_t)(*stop_p) * NTAGS + j];
    const float m = bmax(v + tr);
    const float ss = bsum(__expf(v + tr - m));
    if (j == 0) fs_out[0] = m + __logf(ss);
}

__global__ void crf_out_k(const float* __restrict__ fsp, const float* __restrict__ tsum,
                          const float* __restrict__ part, const float* __restrict__ trans,
                          const int* __restrict__ tags, const int* __restrict__ stop_p,
                          float* __restrict__ out) {
    const int j = threadIdx.x; // 1024
    float e = 0.f;
    for (int cc = 0; cc < 16; ++cc) e += part[cc * NTAGS + j];
    const int stop = *stop_p;
    const int last = tags[SEQLEN - 1];
    out[j] = fsp[0] - (tsum[0] + e + trans[(size_t)stop * NTAGS + last]);
}

extern "C" void kernel_launch(void* const* d_in, const int* in_sizes, int n_in,
                              void* d_out, int out_size, void* d_ws, size_t ws_size,
                              hipStream_t stream) {
    const float* feats = (const float*)d_in[0];
    const float* trans = (const float*)d_in[1];
    const int* tags    = (const int*)d_in[2];
    const int* start_p = (const int*)d_in[3];
    const int* stop_p  = (const int*)d_in[4];
    float* out = (float*)d_out;

    char* ws = (char*)d_ws;
    uint32_t* wbufs = (uint32_t*)(ws + 0);
    float* rm2      = (float*)(ws + 131072);
    float* part     = (float*)(ws + 196608);
    double* Ssum    = (double*)(ws + 262144);
    float* fs       = (float*)(ws + 262272);
    float* tsum     = (float*)(ws + 262276);

    crf_clear_k<<<1, 256, 0, stream>>>(wbufs);
    crf_rowmax_k<<<SEQLEN, 256, 0, stream>>>(feats, rm2);
    crf_emit_k<<<64, 256, 0, stream>>>(feats, tags, part);
    crf_trans_k<<<1, 256, 0, stream>>>(trans, tags, start_p, tsum);
    crf_scan_k<<<NREC * BPR, TPB, 0, stream>>>(feats, trans, wbufs, rm2, Ssum);
    crf_stitch_k<<<1, 1024, 0, stream>>>(wbufs, Ssum, trans, start_p, stop_p, fs);
    crf_out_k<<<1, 1024, 0, stream>>>(fs, tsum, part, trans, tags, stop_p, out);
}